// Round 1
// baseline (478.808 us; speedup 1.0000x reference)
//
#include <hip/hip_runtime.h>

// CausalSelfAttention: B=4, S=2048, D=1024, H=16, HS=64
// x[B,S,D] @ w_qkv[D,3D] + b -> qkv ; per-head causal attn (scale 1/sqrt(H)=0.25) ; @ w_proj + b
// Strategy: bf16 MFMA for all matmuls (threshold 7.5e-2 permits), fp32 accumulate.

typedef unsigned short u16;
typedef short bf16x8 __attribute__((ext_vector_type(8)));
typedef unsigned short u16x8 __attribute__((ext_vector_type(8)));
typedef float f32x4 __attribute__((ext_vector_type(4)));

#define S_LEN 2048
#define DMODEL 1024
#define NHEAD 16
#define HS 64
#define MROWS 8192  // B*S

__device__ __forceinline__ u16 f2bf(float f) {
  union { float f; unsigned u; } c; c.f = f;
  unsigned u = c.u;
  u += 0x7fffu + ((u >> 16) & 1u);  // RNE
  return (u16)(u >> 16);
}

__device__ __forceinline__ f32x4 mfma16(bf16x8 a, bf16x8 b, f32x4 c) {
  return __builtin_amdgcn_mfma_f32_16x16x32_bf16(a, b, c, 0, 0, 0);
}

__device__ __forceinline__ void gload_lds16(const void* g, void* l) {
  __builtin_amdgcn_global_load_lds((__attribute__((address_space(1))) void*)g,
                                   (__attribute__((address_space(3))) void*)l,
                                   16, 0, 0);
}

// ---------------- conversion kernels ----------------
__global__ void k_f32_to_bf16(const float* __restrict__ in, u16* __restrict__ out, int n) {
  int i = (blockIdx.x * 256 + threadIdx.x) * 4;
  if (i < n) {
    float4 v = *reinterpret_cast<const float4*>(in + i);
    ushort4 o;
    o.x = f2bf(v.x); o.y = f2bf(v.y); o.z = f2bf(v.z); o.w = f2bf(v.w);
    *reinterpret_cast<ushort4*>(out + i) = o;
  }
}

// w[K][N] fp32 -> wt[N][K] bf16 (so GEMM uses B^T layout)
__global__ void k_transpose_to_bf16(const float* __restrict__ in, u16* __restrict__ out,
                                    int K, int N) {
  __shared__ float t[32][33];
  int n0 = blockIdx.x * 32, k0 = blockIdx.y * 32;
  int tx = threadIdx.x & 31, ty = threadIdx.x >> 5;  // 32 x 8
#pragma unroll
  for (int i = 0; i < 32; i += 8)
    t[ty + i][tx] = in[(size_t)(k0 + ty + i) * N + n0 + tx];
  __syncthreads();
#pragma unroll
  for (int i = 0; i < 32; i += 8)
    out[(size_t)(n0 + ty + i) * K + k0 + tx] = f2bf(t[tx][ty + i]);
}

// ---------------- GEMM: C[M][N] = A[M][K] * Bt[N][K]^T + bias ----------------
// 128x128 tile, BK=64, 256 threads (4 waves, 2x2 of 64x64), mfma 16x16x32 bf16.
template <bool OUT_BF16>
__global__ __launch_bounds__(256) void k_gemm_bt(const u16* __restrict__ A,
                                                 const u16* __restrict__ Bt,
                                                 const float* __restrict__ bias,
                                                 u16* __restrict__ outb,
                                                 float* __restrict__ outf,
                                                 int N, int K) {
  __shared__ u16 As[128 * 64];  // [row][k] rows of A tile
  __shared__ u16 Bs[128 * 64];  // [col][k] rows of Bt tile
  const int tid = threadIdx.x;
  const int lane = tid & 63, wave = tid >> 6;
  const int wm = wave >> 1, wn = wave & 1;
  const int lr = lane & 15, lk = lane >> 4;
  const int m0 = blockIdx.x * 128, n0 = blockIdx.y * 128;

  f32x4 zero4 = {0.f, 0.f, 0.f, 0.f};
  f32x4 acc[4][4];
#pragma unroll
  for (int m = 0; m < 4; ++m)
#pragma unroll
    for (int n = 0; n < 4; ++n) acc[m][n] = zero4;

  const int nkt = K >> 6;
  for (int kt = 0; kt < nkt; ++kt) {
    const u16* Ag = A + (size_t)m0 * K + kt * 64;
    const u16* Bg = Bt + (size_t)n0 * K + kt * 64;
    // stage A tile: 16KB = 16 chunks of 1KB (64 lanes x 16B), linear LDS
#pragma unroll
    for (int j = 0; j < 4; ++j) {
      int chunk = j * 4 + wave;
      int row = chunk * 8 + (lane >> 3);
      int cole = (lane & 7) * 8;  // u16 units
      gload_lds16(Ag + (size_t)row * K + cole, &As[chunk * 512]);
      gload_lds16(Bg + (size_t)row * K + cole, &Bs[chunk * 512]);
    }
    __syncthreads();
#pragma unroll
    for (int ks = 0; ks < 2; ++ks) {
      bf16x8 af[4], bf[4];
#pragma unroll
      for (int m = 0; m < 4; ++m)
        af[m] = *reinterpret_cast<const bf16x8*>(&As[(wm * 64 + m * 16 + lr) * 64 + ks * 32 + lk * 8]);
#pragma unroll
      for (int n = 0; n < 4; ++n)
        bf[n] = *reinterpret_cast<const bf16x8*>(&Bs[(wn * 64 + n * 16 + lr) * 64 + ks * 32 + lk * 8]);
#pragma unroll
      for (int m = 0; m < 4; ++m)
#pragma unroll
        for (int n = 0; n < 4; ++n) acc[m][n] = mfma16(af[m], bf[n], acc[m][n]);
    }
    __syncthreads();
  }

  // epilogue: D row = (lane>>4)*4 + r, col = lane&15  [verified C/D mapping]
#pragma unroll
  for (int n = 0; n < 4; ++n) {
    int col = n0 + wn * 64 + n * 16 + lr;
    float bv = bias[col];
#pragma unroll
    for (int m = 0; m < 4; ++m) {
#pragma unroll
      for (int r = 0; r < 4; ++r) {
        int row = m0 + wm * 64 + m * 16 + lk * 4 + r;
        float v = acc[m][n][r] + bv;
        if (OUT_BF16)
          outb[(size_t)row * N + col] = f2bf(v);
        else
          outf[(size_t)row * N + col] = v;
      }
    }
  }
}

// ---------------- flash attention ----------------
// grid: (S/64, B*H); block 256 = 4 waves; wave w owns q rows [qt*64+w*16, +16)
__global__ __launch_bounds__(256) void k_attn(const u16* __restrict__ qkv,
                                              u16* __restrict__ ao) {
  __shared__ u16 Qs[64 * 64];      // [q][hs]
  __shared__ u16 Ks[64 * 64];      // [key][hs]
  __shared__ u16 Vs[64 * 64];      // grouped: [g=key/8][hs][key%8]
  __shared__ u16 Ps[4][16 * 64];   // per-wave P tile [q][key]

  const int tid = threadIdx.x;
  const int lane = tid & 63, wave = tid >> 6;
  const int lr = lane & 15, lk = lane >> 4;
  const int qt = blockIdx.x, bh = blockIdx.y;
  const int b = bh >> 4, h = bh & 15;
  const size_t rowbase = (size_t)b * S_LEN * 3072;
  const int qcol = h * 64, kcol = 1024 + h * 64, vcol = 2048 + h * 64;

  // stage Q tile
  for (int i = tid; i < 512; i += 256) {
    int row = i >> 3, c = i & 7;
    *reinterpret_cast<u16x8*>(&Qs[row * 64 + c * 8]) =
        *reinterpret_cast<const u16x8*>(qkv + rowbase + (size_t)(qt * 64 + row) * 3072 + qcol + c * 8);
  }
  __syncthreads();
  bf16x8 qf[2];
  qf[0] = *reinterpret_cast<const bf16x8*>(&Qs[(wave * 16 + lr) * 64 + lk * 8]);
  qf[1] = *reinterpret_cast<const bf16x8*>(&Qs[(wave * 16 + lr) * 64 + 32 + lk * 8]);

  f32x4 zero4 = {0.f, 0.f, 0.f, 0.f};
  f32x4 oacc[4];
#pragma unroll
  for (int n = 0; n < 4; ++n) oacc[n] = zero4;
  float m_i[4], l_i[4];
#pragma unroll
  for (int r = 0; r < 4; ++r) { m_i[r] = -INFINITY; l_i[r] = 0.f; }

  for (int kt = 0; kt <= qt; ++kt) {
    __syncthreads();  // previous compute done before K/V overwrite
    for (int i = tid; i < 512; i += 256) {
      int row = i >> 3, c = i & 7;
      *reinterpret_cast<u16x8*>(&Ks[row * 64 + c * 8]) =
          *reinterpret_cast<const u16x8*>(qkv + rowbase + (size_t)(kt * 64 + row) * 3072 + kcol + c * 8);
    }
    for (int i = tid; i < 512; i += 256) {
      int key = i >> 3, c = i & 7;
      u16x8 v = *reinterpret_cast<const u16x8*>(qkv + rowbase + (size_t)(kt * 64 + key) * 3072 + vcol + c * 8);
      int g = key >> 3, e = key & 7;
#pragma unroll
      for (int j = 0; j < 8; ++j) Vs[(g * 64 + c * 8 + j) * 8 + e] = v[j];
    }
    __syncthreads();

    // S = Q K^T : 4 col-frags (16 keys each) x 2 ksteps
    f32x4 sc[4];
#pragma unroll
    for (int c = 0; c < 4; ++c) sc[c] = zero4;
#pragma unroll
    for (int ks = 0; ks < 2; ++ks)
#pragma unroll
      for (int c = 0; c < 4; ++c) {
        bf16x8 kf = *reinterpret_cast<const bf16x8*>(&Ks[(c * 16 + lr) * 64 + ks * 32 + lk * 8]);
        sc[c] = mfma16(qf[ks], kf, sc[c]);
      }

    // scale + causal mask
    float s[4][4];
    const int qrow = qt * 64 + wave * 16 + lk * 4;
#pragma unroll
    for (int c = 0; c < 4; ++c)
#pragma unroll
      for (int r = 0; r < 4; ++r) {
        float v = sc[c][r] * 0.25f;
        if (kt == qt && (kt * 64 + c * 16 + lr) > (qrow + r)) v = -INFINITY;
        s[c][r] = v;
      }

    // online softmax: row stats via 16-lane butterfly
    float rmax[4], rsum[4], corr[4];
#pragma unroll
    for (int r = 0; r < 4; ++r) {
      float mx = fmaxf(fmaxf(s[0][r], s[1][r]), fmaxf(s[2][r], s[3][r]));
#pragma unroll
      for (int off = 1; off < 16; off <<= 1) mx = fmaxf(mx, __shfl_xor(mx, off, 64));
      float mnew = fmaxf(m_i[r], mx);
      corr[r] = __expf(m_i[r] - mnew);
      m_i[r] = mnew;
      l_i[r] *= corr[r];
      rsum[r] = 0.f;
    }
    u16 pb[4][4];
#pragma unroll
    for (int c = 0; c < 4; ++c)
#pragma unroll
      for (int r = 0; r < 4; ++r) {
        float p = __expf(s[c][r] - m_i[r]);
        rsum[r] += p;
        pb[c][r] = f2bf(p);
      }
#pragma unroll
    for (int r = 0; r < 4; ++r) {
#pragma unroll
      for (int off = 1; off < 16; off <<= 1) rsum[r] += __shfl_xor(rsum[r], off, 64);
      l_i[r] += rsum[r];
    }
    f32x4 cv = {corr[0], corr[1], corr[2], corr[3]};
#pragma unroll
    for (int n = 0; n < 4; ++n) oacc[n] *= cv;

    // P -> LDS (per-wave region), then PV
#pragma unroll
    for (int c = 0; c < 4; ++c)
#pragma unroll
      for (int r = 0; r < 4; ++r) Ps[wave][(lk * 4 + r) * 64 + c * 16 + lr] = pb[c][r];

#pragma unroll
    for (int ks = 0; ks < 2; ++ks) {
      bf16x8 pa = *reinterpret_cast<const bf16x8*>(&Ps[wave][lr * 64 + ks * 32 + lk * 8]);
#pragma unroll
      for (int n = 0; n < 4; ++n) {
        bf16x8 vb = *reinterpret_cast<const bf16x8*>(&Vs[((lk + ks * 4) * 64 + n * 16 + lr) * 8]);
        oacc[n] = mfma16(pa, vb, oacc[n]);
      }
    }
  }

  // epilogue: out[b, q, h, hs]
  float inv[4];
#pragma unroll
  for (int r = 0; r < 4; ++r) inv[r] = 1.f / l_i[r];
#pragma unroll
  for (int n = 0; n < 4; ++n)
#pragma unroll
    for (int r = 0; r < 4; ++r) {
      int row = qt * 64 + wave * 16 + lk * 4 + r;
      int col = h * 64 + n * 16 + lr;
      ao[((size_t)b * S_LEN + row) * DMODEL + col] = f2bf(oacc[n][r] * inv[r]);
    }
}

// ---------------- launch ----------------
extern "C" void kernel_launch(void* const* d_in, const int* in_sizes, int n_in,
                              void* d_out, int out_size, void* d_ws, size_t ws_size,
                              hipStream_t stream) {
  const float* x = (const float*)d_in[0];
  const float* wqkv = (const float*)d_in[1];
  const float* bqkv = (const float*)d_in[2];
  const float* wproj = (const float*)d_in[3];
  const float* bproj = (const float*)d_in[4];
  float* out = (float*)d_out;

  char* ws = (char*)d_ws;
  u16* Xb     = (u16*)(ws);                       // [8192][1024] bf16, 16 MiB
  u16* Wqkvt  = (u16*)(ws + (size_t)16777216);    // [3072][1024] bf16,  6 MiB
  u16* Wprojt = (u16*)(ws + (size_t)23068672);    // [1024][1024] bf16,  2 MiB
  u16* QKVb   = (u16*)(ws + (size_t)25165824);    // [8192][3072] bf16, 48 MiB
  u16* AOb    = (u16*)(ws + (size_t)75497472);    // [8192][1024] bf16, 16 MiB

  // convert / transpose weights+activations to bf16
  k_f32_to_bf16<<<MROWS * DMODEL / 4 / 256, 256, 0, stream>>>(x, Xb, MROWS * DMODEL);
  k_transpose_to_bf16<<<dim3(3072 / 32, 1024 / 32), 256, 0, stream>>>(wqkv, Wqkvt, 1024, 3072);
  k_transpose_to_bf16<<<dim3(1024 / 32, 1024 / 32), 256, 0, stream>>>(wproj, Wprojt, 1024, 1024);

  // qkv = x @ w_qkv + b  (bf16 out)
  k_gemm_bt<true><<<dim3(MROWS / 128, 3072 / 128), 256, 0, stream>>>(
      Xb, Wqkvt, bqkv, QKVb, nullptr, 3072, 1024);

  // causal flash attention per (b,h)
  k_attn<<<dim3(S_LEN / 64, 4 * NHEAD), 256, 0, stream>>>(QKVb, AOb);

  // out = ao @ w_proj + b  (fp32 out)
  k_gemm_bt<false><<<dim3(MROWS / 128, DMODEL / 128), 256, 0, stream>>>(
      AOb, Wprojt, bproj, nullptr, out, DMODEL, 1024);
}

// Round 2
// 325.165 us; speedup vs baseline: 1.4725x; 1.4725x over previous
//
#include <hip/hip_runtime.h>

// CausalSelfAttention: B=4, S=2048, D=1024, H=16, HS=64
// x @ w_qkv + b -> qkv ; per-head causal attn (scale 1/sqrt(H)=0.25) ; @ w_proj + b
// bf16 MFMA everywhere, fp32 accumulate.

typedef unsigned short u16;
typedef short bf16x8 __attribute__((ext_vector_type(8)));
typedef unsigned short u16x8 __attribute__((ext_vector_type(8)));
typedef float f32x4 __attribute__((ext_vector_type(4)));

#define S_LEN 2048
#define DMODEL 1024
#define NHEAD 16
#define MROWS 8192  // B*S

__device__ __forceinline__ u16 f2bf(float f) {
  union { float f; unsigned u; } c; c.f = f;
  unsigned u = c.u;
  u += 0x7fffu + ((u >> 16) & 1u);  // RNE
  return (u16)(u >> 16);
}

__device__ __forceinline__ f32x4 mfma16(bf16x8 a, bf16x8 b, f32x4 c) {
  return __builtin_amdgcn_mfma_f32_16x16x32_bf16(a, b, c, 0, 0, 0);
}

__device__ __forceinline__ void gload_lds16(const void* g, void* l) {
  __builtin_amdgcn_global_load_lds((__attribute__((address_space(1))) void*)g,
                                   (__attribute__((address_space(3))) void*)l,
                                   16, 0, 0);
}

// ---------------- conversion kernels ----------------
__global__ void k_f32_to_bf16(const float* __restrict__ in, u16* __restrict__ out, int n) {
  int i = (blockIdx.x * 256 + threadIdx.x) * 4;
  if (i < n) {
    float4 v = *reinterpret_cast<const float4*>(in + i);
    ushort4 o;
    o.x = f2bf(v.x); o.y = f2bf(v.y); o.z = f2bf(v.z); o.w = f2bf(v.w);
    *reinterpret_cast<ushort4*>(out + i) = o;
  }
}

// w[K][N] fp32 -> wt[N][K] bf16
__global__ void k_transpose_to_bf16(const float* __restrict__ in, u16* __restrict__ out,
                                    int K, int N) {
  __shared__ float t[32][33];
  int n0 = blockIdx.x * 32, k0 = blockIdx.y * 32;
  int tx = threadIdx.x & 31, ty = threadIdx.x >> 5;  // 32 x 8
#pragma unroll
  for (int i = 0; i < 32; i += 8)
    t[ty + i][tx] = in[(size_t)(k0 + ty + i) * N + n0 + tx];
  __syncthreads();
#pragma unroll
  for (int i = 0; i < 32; i += 8)
    out[(size_t)(n0 + ty + i) * K + k0 + tx] = f2bf(t[tx][ty + i]);
}

// V part of qkv -> Vt[(b*16+h)*64 + d][s within b]  (bf16)
__global__ void k_vt(const u16* __restrict__ qkv, u16* __restrict__ vt) {
  __shared__ u16 t[64][65];  // odd stride: conflict-light both directions
  const int tid = threadIdx.x;
  const int s0 = blockIdx.x * 64;
  const int bh = blockIdx.y, b = bh >> 4, h = bh & 15;
  const size_t inbase = (size_t)b * S_LEN * 3072 + 2048 + h * 64;
  for (int i = tid; i < 512; i += 256) {
    int row = i >> 3, c = i & 7;
    u16x8 v = *reinterpret_cast<const u16x8*>(qkv + inbase + (size_t)(s0 + row) * 3072 + c * 8);
#pragma unroll
    for (int j = 0; j < 8; ++j) t[row][c * 8 + j] = v[j];
  }
  __syncthreads();
  const size_t outbase = (size_t)bh * 64 * S_LEN + s0;
  for (int i = tid; i < 512; i += 256) {
    int d = i >> 3, c = i & 7;
    u16x8 o;
#pragma unroll
    for (int j = 0; j < 8; ++j) o[j] = t[c * 8 + j][d];
    *reinterpret_cast<u16x8*>(vt + outbase + (size_t)d * S_LEN + c * 8) = o;
  }
}

// ---------------- GEMM: C[M][N] = A[M][K] * Bt[N][K]^T + bias ----------------
template <bool OUT_BF16>
__global__ __launch_bounds__(256) void k_gemm_bt(const u16* __restrict__ A,
                                                 const u16* __restrict__ Bt,
                                                 const float* __restrict__ bias,
                                                 u16* __restrict__ outb,
                                                 float* __restrict__ outf,
                                                 int N, int K) {
  __shared__ u16 As[128 * 64];
  __shared__ u16 Bs[128 * 64];
  const int tid = threadIdx.x;
  const int lane = tid & 63, wave = tid >> 6;
  const int wm = wave >> 1, wn = wave & 1;
  const int lr = lane & 15, lk = lane >> 4;
  const int m0 = blockIdx.x * 128, n0 = blockIdx.y * 128;

  f32x4 zero4 = {0.f, 0.f, 0.f, 0.f};
  f32x4 acc[4][4];
#pragma unroll
  for (int m = 0; m < 4; ++m)
#pragma unroll
    for (int n = 0; n < 4; ++n) acc[m][n] = zero4;

  const int nkt = K >> 6;
  for (int kt = 0; kt < nkt; ++kt) {
    const u16* Ag = A + (size_t)m0 * K + kt * 64;
    const u16* Bg = Bt + (size_t)n0 * K + kt * 64;
#pragma unroll
    for (int j = 0; j < 4; ++j) {
      int chunk = j * 4 + wave;
      int row = chunk * 8 + (lane >> 3);
      int cole = (lane & 7) * 8;
      gload_lds16(Ag + (size_t)row * K + cole, &As[chunk * 512]);
      gload_lds16(Bg + (size_t)row * K + cole, &Bs[chunk * 512]);
    }
    __syncthreads();
#pragma unroll
    for (int ks = 0; ks < 2; ++ks) {
      bf16x8 af[4], bfr[4];
#pragma unroll
      for (int m = 0; m < 4; ++m)
        af[m] = *reinterpret_cast<const bf16x8*>(&As[(wm * 64 + m * 16 + lr) * 64 + ks * 32 + lk * 8]);
#pragma unroll
      for (int n = 0; n < 4; ++n)
        bfr[n] = *reinterpret_cast<const bf16x8*>(&Bs[(wn * 64 + n * 16 + lr) * 64 + ks * 32 + lk * 8]);
#pragma unroll
      for (int m = 0; m < 4; ++m)
#pragma unroll
        for (int n = 0; n < 4; ++n) acc[m][n] = mfma16(af[m], bfr[n], acc[m][n]);
    }
    __syncthreads();
  }

#pragma unroll
  for (int n = 0; n < 4; ++n) {
    int col = n0 + wn * 64 + n * 16 + lr;
    float bv = bias[col];
#pragma unroll
    for (int m = 0; m < 4; ++m) {
#pragma unroll
      for (int r = 0; r < 4; ++r) {
        int row = m0 + wm * 64 + m * 16 + lk * 4 + r;
        float v = acc[m][n][r] + bv;
        if (OUT_BF16)
          outb[(size_t)row * N + col] = f2bf(v);
        else
          outf[(size_t)row * N + col] = v;
      }
    }
  }
}

// ---------------- flash attention, barrier-free ----------------
// grid 1024: bh = gid&63, qt = gid>>6 (16 q-tiles of 128). Block 256 = 4 waves.
// Wave owns 32 q rows (two 16-row m-groups). K frags direct from global (L2-hot),
// V frags direct from Vt. P via per-wave LDS with XOR swizzle. No __syncthreads.
__global__ __launch_bounds__(256) void k_attn2(const u16* __restrict__ qkv,
                                               const u16* __restrict__ vt,
                                               u16* __restrict__ ao) {
  __shared__ unsigned char PsB[4][4096];  // per-wave 32 rows x 128B, swizzled
  const int tid = threadIdx.x;
  const int lane = tid & 63, wave = tid >> 6;
  const int lr = lane & 15, lk = lane >> 4;
  const int gid = blockIdx.x;
  const int bh = gid & 63, qt = gid >> 6;
  const int b = bh >> 4, h = bh & 15;
  const size_t rowb = (size_t)b * S_LEN * 3072;
  const int qcol = h * 64, kcol = 1024 + h * 64;
  const u16* vbase = vt + (size_t)bh * 64 * S_LEN;
  const int q0 = qt * 128 + wave * 32;
  unsigned char* myP = PsB[wave];

  // Q fragments, direct from global
  bf16x8 qf[2][2];
#pragma unroll
  for (int m = 0; m < 2; ++m)
#pragma unroll
    for (int ks = 0; ks < 2; ++ks)
      qf[m][ks] = *reinterpret_cast<const bf16x8*>(
          qkv + rowb + (size_t)(q0 + m * 16 + lr) * 3072 + qcol + ks * 32 + lk * 8);

  f32x4 zero4 = {0.f, 0.f, 0.f, 0.f};
  f32x4 oacc[2][4];
  float m_i[2][4], l_i[2][4];
#pragma unroll
  for (int m = 0; m < 2; ++m) {
#pragma unroll
    for (int n = 0; n < 4; ++n) oacc[m][n] = zero4;
#pragma unroll
    for (int r = 0; r < 4; ++r) { m_i[m][r] = -INFINITY; l_i[m][r] = 0.f; }
  }

  const int ktmax = (q0 + 31) >> 6;
  for (int kt = 0; kt <= ktmax; ++kt) {
    // ---- QK^T ----
    f32x4 sc[2][4];
#pragma unroll
    for (int m = 0; m < 2; ++m)
#pragma unroll
      for (int c = 0; c < 4; ++c) sc[m][c] = zero4;
#pragma unroll
    for (int ks = 0; ks < 2; ++ks)
#pragma unroll
      for (int c = 0; c < 4; ++c) {
        bf16x8 kf = *reinterpret_cast<const bf16x8*>(
            qkv + rowb + (size_t)(kt * 64 + c * 16 + lr) * 3072 + kcol + ks * 32 + lk * 8);
        sc[0][c] = mfma16(qf[0][ks], kf, sc[0][c]);
        sc[1][c] = mfma16(qf[1][ks], kf, sc[1][c]);
      }

    // ---- V frags issued early: latency hides under softmax ----
    bf16x8 vb[2][4];
#pragma unroll
    for (int ks = 0; ks < 2; ++ks)
#pragma unroll
      for (int n = 0; n < 4; ++n)
        vb[ks][n] = *reinterpret_cast<const bf16x8*>(
            vbase + (size_t)(n * 16 + lr) * S_LEN + kt * 64 + ks * 32 + lk * 8);

    const bool edge = (kt == ktmax);
    // ---- online softmax + P store (per m-group) ----
#pragma unroll
    for (int m = 0; m < 2; ++m) {
      float s[4][4];
      const int qrow = q0 + m * 16 + lk * 4;
#pragma unroll
      for (int c = 0; c < 4; ++c)
#pragma unroll
        for (int r = 0; r < 4; ++r) {
          float v = sc[m][c][r] * 0.25f;
          if (edge && (kt * 64 + c * 16 + lr) > (qrow + r)) v = -INFINITY;
          s[c][r] = v;
        }
      float corr[4], rsum[4];
#pragma unroll
      for (int r = 0; r < 4; ++r) {
        float mx = fmaxf(fmaxf(s[0][r], s[1][r]), fmaxf(s[2][r], s[3][r]));
#pragma unroll
        for (int off = 1; off < 16; off <<= 1) mx = fmaxf(mx, __shfl_xor(mx, off, 64));
        float mnew = fmaxf(m_i[m][r], mx);
        corr[r] = __expf(m_i[m][r] - mnew);
        m_i[m][r] = mnew;
        l_i[m][r] *= corr[r];
        rsum[r] = 0.f;
      }
#pragma unroll
      for (int c = 0; c < 4; ++c)
#pragma unroll
        for (int r = 0; r < 4; ++r) {
          float p = __expf(s[c][r] - m_i[m][r]);
          rsum[r] += p;
          int row = m * 16 + lk * 4 + r;
          int off = row * 128 + (c * 16 + lr) * 2;
          *reinterpret_cast<u16*>(myP + (off ^ ((row & 7) << 4))) = f2bf(p);
        }
#pragma unroll
      for (int r = 0; r < 4; ++r) {
#pragma unroll
        for (int off = 1; off < 16; off <<= 1) rsum[r] += __shfl_xor(rsum[r], off, 64);
        l_i[m][r] += rsum[r];
      }
      f32x4 cv = {corr[0], corr[1], corr[2], corr[3]};
#pragma unroll
      for (int n = 0; n < 4; ++n) oacc[m][n] *= cv;
    }

    // ---- PV ----
    bf16x8 pa[2][2];
#pragma unroll
    for (int m = 0; m < 2; ++m)
#pragma unroll
      for (int ks = 0; ks < 2; ++ks) {
        int row = m * 16 + lr;
        int off = row * 128 + ks * 64 + lk * 16;
        pa[m][ks] = *reinterpret_cast<const bf16x8*>(myP + (off ^ ((row & 7) << 4)));
      }
#pragma unroll
    for (int ks = 0; ks < 2; ++ks)
#pragma unroll
      for (int n = 0; n < 4; ++n) {
        oacc[0][n] = mfma16(pa[0][ks], vb[ks][n], oacc[0][n]);
        oacc[1][n] = mfma16(pa[1][ks], vb[ks][n], oacc[1][n]);
      }
  }

  // ---- epilogue ----
#pragma unroll
  for (int m = 0; m < 2; ++m) {
    float inv[4];
#pragma unroll
    for (int r = 0; r < 4; ++r) inv[r] = 1.f / l_i[m][r];
#pragma unroll
    for (int n = 0; n < 4; ++n)
#pragma unroll
      for (int r = 0; r < 4; ++r) {
        int row = q0 + m * 16 + lk * 4 + r;
        int col = h * 64 + n * 16 + lr;
        ao[((size_t)b * S_LEN + row) * DMODEL + col] = f2bf(oacc[m][n][r] * inv[r]);
      }
  }
}

// ---------------- launch ----------------
extern "C" void kernel_launch(void* const* d_in, const int* in_sizes, int n_in,
                              void* d_out, int out_size, void* d_ws, size_t ws_size,
                              hipStream_t stream) {
  const float* x = (const float*)d_in[0];
  const float* wqkv = (const float*)d_in[1];
  const float* bqkv = (const float*)d_in[2];
  const float* wproj = (const float*)d_in[3];
  const float* bproj = (const float*)d_in[4];
  float* out = (float*)d_out;

  char* ws = (char*)d_ws;
  u16* Xb     = (u16*)(ws);                       // [8192][1024] bf16, 16 MiB
  u16* Wqkvt  = (u16*)(ws + (size_t)16777216);    // [3072][1024] bf16,  6 MiB
  u16* Wprojt = (u16*)(ws + (size_t)23068672);    // [1024][1024] bf16,  2 MiB
  u16* QKVb   = (u16*)(ws + (size_t)25165824);    // [8192][3072] bf16, 48 MiB
  u16* AOb    = (u16*)(ws + (size_t)75497472);    // [8192][1024] bf16, 16 MiB
  u16* Vt     = Xb;  // reuse: Xb dead after GEMM1, Vt written after GEMM1

  k_f32_to_bf16<<<MROWS * DMODEL / 4 / 256, 256, 0, stream>>>(x, Xb, MROWS * DMODEL);
  k_transpose_to_bf16<<<dim3(3072 / 32, 1024 / 32), 256, 0, stream>>>(wqkv, Wqkvt, 1024, 3072);
  k_transpose_to_bf16<<<dim3(1024 / 32, 1024 / 32), 256, 0, stream>>>(wproj, Wprojt, 1024, 1024);

  // qkv = x @ w_qkv + b  (bf16 out)
  k_gemm_bt<true><<<dim3(MROWS / 128, 3072 / 128), 256, 0, stream>>>(
      Xb, Wqkvt, bqkv, QKVb, nullptr, 3072, 1024);

  // V transpose for PV B-frags
  k_vt<<<dim3(S_LEN / 64, 4 * NHEAD), 256, 0, stream>>>(QKVb, Vt);

  // causal flash attention
  k_attn2<<<dim3(1024), 256, 0, stream>>>(QKVb, Vt, AOb);

  // out = ao @ w_proj + b  (fp32 out)
  k_gemm_bt<false><<<dim3(MROWS / 128, DMODEL / 128), 256, 0, stream>>>(
      AOb, Wprojt, bproj, nullptr, out, DMODEL, 1024);
}